// Round 1
// baseline (225.410 us; speedup 1.0000x reference)
//
#include <hip/hip_runtime.h>

typedef unsigned short u16;
typedef unsigned char u8;
typedef float f32x4 __attribute__((ext_vector_type(4)));
typedef __bf16 bf16x8 __attribute__((ext_vector_type(8)));

#define ELEMS 25165824   // T*B*C*N = 4*16*384*1024
#define COLS_B 4096      // N*T per batch element
#define ONE_BF16 ((u16)0x3F80)

// ---- async global->LDS, 16B per lane, dest = wave-uniform base + lane*16 ----
__device__ __forceinline__ void gll16(const void* g, void* l) {
  __builtin_amdgcn_global_load_lds((const __attribute__((address_space(1))) void*)g,
                                   (__attribute__((address_space(3))) void*)l, 16, 0, 0);
}

// quad_perm broadcast of lane K within each 4-lane quad
template <int CTRL>
__device__ __forceinline__ float quadb(float x) {
  return __int_as_float(__builtin_amdgcn_update_dpp(0, __float_as_int(x), CTRL, 0xF, 0xF, true));
}

// ---------------- K0: weights -> bf16 (stacked q,k,v), BN params fused ----------------
__global__ __launch_bounds__(256) void k_convert(
    const float* __restrict__ qw, const float* __restrict__ kw,
    const float* __restrict__ vw, const float* __restrict__ pw,
    const float* __restrict__ qg, const float* __restrict__ qbt,
    const float* __restrict__ qm, const float* __restrict__ qv,
    const float* __restrict__ kg, const float* __restrict__ kbt,
    const float* __restrict__ km, const float* __restrict__ kv,
    const float* __restrict__ vg, const float* __restrict__ vbt,
    const float* __restrict__ vm, const float* __restrict__ vv,
    const float* __restrict__ pg, const float* __restrict__ pbt,
    const float* __restrict__ pm, const float* __restrict__ pv,
    const float* __restrict__ pbias,
    u16* __restrict__ Wstk, u16* __restrict__ Pw,
    float4* __restrict__ BNP, float4* __restrict__ PP) {
  int tid = blockIdx.x * 256 + threadIdx.x;
  if (tid < 442368) {               // Wstk[1152][384]
    int r = tid / 384, c = tid - r * 384;
    const float* src = (r < 384) ? qw : (r < 768) ? kw : vw;
    int rr = (r >= 768) ? r - 768 : (r >= 384) ? r - 384 : r;
    unsigned int u = __float_as_uint(src[rr * 384 + c]);
    u = (u + 0x7FFFu + ((u >> 16) & 1u)) >> 16;   // RNE to bf16
    Wstk[tid] = (u16)u;
  } else if (tid < 589824) {        // Pw[384][384]
    int i = tid - 442368;
    unsigned int u = __float_as_uint(pw[i]);
    u = (u + 0x7FFFu + ((u >> 16) & 1u)) >> 16;
    Pw[i] = (u16)u;
  } else if (tid < 590976) {        // BNP[1152] = {inv, mean, beta, -}
    int r = tid - 589824;
    int br = r / 384, ch = r - br * 384;
    const float* g  = (br == 0) ? qg  : (br == 1) ? kg  : vg;
    const float* bt = (br == 0) ? qbt : (br == 1) ? kbt : vbt;
    const float* m  = (br == 0) ? qm  : (br == 1) ? km  : vm;
    const float* va = (br == 0) ? qv  : (br == 1) ? kv  : vv;
    float inv = g[ch] / sqrtf(va[ch] + 1e-5f);
    BNP[r] = make_float4(inv, m[ch], bt[ch], 0.f);
  } else if (tid < 591360) {        // PP[384] = {inv, mean, beta, bias}
    int ch = tid - 590976;
    float inv = pg[ch] / sqrtf(pv[ch] + 1e-5f);
    PP[ch] = make_float4(inv, pm[ch], pbt[ch], pbias[ch]);
  }
}

// ---------------- K1: input LIF + transpose (T,B,C,N)->(B,N,T,C) bf16 spikes ----------
__global__ __launch_bounds__(256) void k_lif_in(const float* __restrict__ x, u16* __restrict__ xs) {
  const int nt = blockIdx.x, ct = blockIdx.y, b = blockIdx.z;
  const int tid = threadIdx.x;
  const int nj = tid & 63, cr = tid >> 6;
  const int c0 = ct * 64, n0 = nt * 64;
  __shared__ u16 spl[16384];        // [nj][t][ci], ci XOR-swizzled by nj (quad-preserving)
  float v[16];
  #pragma unroll
  for (int i = 0; i < 16; ++i) v[i] = 0.f;
  for (int t = 0; t < 4; ++t) {
    const float* xr = x + (((t * 16 + b) * 384 + c0 + cr) * 1024) + n0 + nj;
    #pragma unroll
    for (int it = 0; it < 16; ++it) {
      float xv = xr[it * 4096];
      float vv = v[it];
      float h = __fadd_rn(vv, __fmul_rn(__fsub_rn(xv, vv), 0.5f));  // v + (x-v)/2, exact order
      bool s = h >= 1.f;
      v[it] = s ? 0.f : h;
      int ci = cr + it * 4;
      spl[((nj * 4 + t) << 6) | (ci ^ ((nj & 15) << 2))] = s ? ONE_BF16 : (u16)0;
    }
  }
  __syncthreads();
  #pragma unroll
  for (int kk = 0; kk < 16; ++kk) {
    int f = tid + kk * 256;
    int ci4 = f & 15, tt = (f >> 4) & 3, njj = f >> 6;
    ushort4 d = *(const ushort4*)&spl[((njj * 4 + tt) << 6) + ((ci4 * 4) ^ ((njj & 15) << 2))];
    *(ushort4*)&xs[((b * 1024 + n0 + njj) * 4 + tt) * 384 + c0 + ci4 * 4] = d;
  }
}

// ---------------- K2: stacked qkv GEMM (1152x384 @ 384xcols) + BN + LIF -> spike bytes -
__global__ __launch_bounds__(256) void k_qkv(
    const u16* __restrict__ Wstk, const u16* __restrict__ xs,
    const float4* __restrict__ BNP, u8* __restrict__ sp) {
  const int jt = blockIdx.x, mt = blockIdx.y, b = blockIdx.z;
  const int tid = threadIdx.x;
  const int w = tid >> 6, l = tid & 63;
  const int wr = w >> 1, wc = w & 1;
  const int l15 = l & 15, g = l >> 4;
  const int m0 = mt * 128, j0 = jt * 128;

  __shared__ u16 Al[4096];          // [128][32]
  __shared__ u16 Bl[4096];          // [128 cols][32 k]
  __shared__ u8 SP[128 * 144];      // spike transpose buffer, padded rows
  __shared__ float4 PRM[128];

  const u16* xb = xs + b * (COLS_B * 384);

  f32x4 acc[4][4];
  const f32x4 zero = {0.f, 0.f, 0.f, 0.f};
  #pragma unroll
  for (int mi = 0; mi < 4; ++mi)
    #pragma unroll
    for (int ni = 0; ni < 4; ++ni) acc[mi][ni] = zero;

  for (int ks = 0; ks < 12; ++ks) {
    const int k0 = ks * 32;
    #pragma unroll
    for (int q = 0; q < 2; ++q) {
      const int ch = w * 128 + q * 64 + l;
      const int row = ch >> 2, kc = (ch & 3) << 3;
      gll16(Wstk + (m0 + row) * 384 + k0 + kc, &Al[(w * 128 + q * 64) * 8]);
      gll16(xb + (j0 + row) * 384 + k0 + kc, &Bl[(w * 128 + q * 64) * 8]);
    }
    __syncthreads();
    bf16x8 af[4], bfr[4];
    #pragma unroll
    for (int mi = 0; mi < 4; ++mi)
      af[mi] = *(const bf16x8*)&Al[(wr * 64 + mi * 16 + l15) * 32 + g * 8];
    #pragma unroll
    for (int ni = 0; ni < 4; ++ni)
      bfr[ni] = *(const bf16x8*)&Bl[(wc * 64 + ni * 16 + l15) * 32 + g * 8];
    #pragma unroll
    for (int mi = 0; mi < 4; ++mi)
      #pragma unroll
      for (int ni = 0; ni < 4; ++ni)
        acc[mi][ni] = __builtin_amdgcn_mfma_f32_16x16x32_bf16(af[mi], bfr[ni], acc[mi][ni], 0, 0, 0);
    __syncthreads();
  }

  if (tid < 128) PRM[tid] = BNP[m0 + tid];
  __syncthreads();

  const int tq = l & 3;             // column's timestep lives in the low 2 lane bits
  #pragma unroll
  for (int mi = 0; mi < 4; ++mi) {
    float4 pr0 = PRM[wr * 64 + mi * 16 + g * 4 + 0];
    float4 pr1 = PRM[wr * 64 + mi * 16 + g * 4 + 1];
    float4 pr2 = PRM[wr * 64 + mi * 16 + g * 4 + 2];
    float4 pr3 = PRM[wr * 64 + mi * 16 + g * 4 + 3];
    #pragma unroll
    for (int ni = 0; ni < 4; ++ni) {
      unsigned int bytes = 0;
      #pragma unroll
      for (int r = 0; r < 4; ++r) {
        float4 pr = (r == 0) ? pr0 : (r == 1) ? pr1 : (r == 2) ? pr2 : pr3;
        float y = acc[mi][ni][r];
        float z = __fadd_rn(__fmul_rn(__fsub_rn(y, pr.y), pr.x), pr.z);   // BN, ref order
        float z0 = quadb<0x00>(z), z1 = quadb<0x55>(z), z2 = quadb<0xAA>(z), z3 = quadb<0xFF>(z);
        float h0 = __fmul_rn(z0, 0.5f);
        bool s0 = h0 >= 1.f;  float v1 = s0 ? 0.f : h0;
        float h1 = __fadd_rn(v1, __fmul_rn(__fsub_rn(z1, v1), 0.5f));
        bool s1 = h1 >= 1.f;  float v2 = s1 ? 0.f : h1;
        float h2 = __fadd_rn(v2, __fmul_rn(__fsub_rn(z2, v2), 0.5f));
        bool s2 = h2 >= 1.f;  float v3 = s2 ? 0.f : h2;
        float h3 = __fadd_rn(v3, __fmul_rn(__fsub_rn(z3, v3), 0.5f));
        bool s3 = h3 >= 1.f;
        bool smine = (tq == 0) ? s0 : (tq == 1) ? s1 : (tq == 2) ? s2 : s3;
        bytes |= (smine ? 1u : 0u) << (r * 8);
      }
      const int jc = wc * 64 + ni * 16 + l15;
      *(unsigned int*)&SP[jc * 144 + wr * 64 + mi * 16 + g * 4] = bytes;
    }
  }
  __syncthreads();

  const int br = mt / 3;
  const int cb = (mt - br * 3) * 128;
  u8* spb = sp + br * ELEMS + (b * COLS_B + j0) * 384 + cb;
  const int row = tid >> 1, half = tid & 1;
  #pragma unroll
  for (int qq = 0; qq < 4; ++qq) {
    uint4 d = *(const uint4*)&SP[row * 144 + half * 64 + qq * 16];
    *(uint4*)&spb[row * 384 + half * 64 + qq * 16] = d;
  }
}

// ---------------- K3a: attn = sum_ch(k*v) per head, LIF(0.5), xp = q*attn (bf16) ------
__global__ __launch_bounds__(256) void k_attn(const u8* __restrict__ sp, u16* __restrict__ xp) {
  const int gw = blockIdx.x * 4 + (threadIdx.x >> 6);
  const int l = threadIdx.x & 63;
  const int b = gw >> 10, n = gw & 1023;
  const u8* qB = sp;
  const u8* kB = sp + ELEMS;
  const u8* vB = sp + 2 * ELEMS;
  const int base_n = (b * 1024 + n) * 4 * 384;
  float vst = 0.f;                  // one head per 8-lane group; redundant per lane
  for (int t = 0; t < 4; ++t) {
    const int ro = base_n + t * 384 + l * 6;
    int s = 0;
    #pragma unroll
    for (int i = 0; i < 6; ++i) s += (int)kB[ro + i] * (int)vB[ro + i];
    s += __shfl_xor(s, 1);
    s += __shfl_xor(s, 2);
    s += __shfl_xor(s, 4);          // 8 lanes == one 48-channel head
    float attn = (float)s;
    float h = __fadd_rn(vst, __fmul_rn(__fsub_rn(attn, vst), 0.5f));
    bool sk = h >= 0.5f;
    vst = sk ? 0.f : h;
    unsigned int wv0, wv1, wv2;
    wv0 = ((sk && qB[ro + 0]) ? 0x3F80u : 0u) | (((sk && qB[ro + 1]) ? 0x3F80u : 0u) << 16);
    wv1 = ((sk && qB[ro + 2]) ? 0x3F80u : 0u) | (((sk && qB[ro + 3]) ? 0x3F80u : 0u) << 16);
    wv2 = ((sk && qB[ro + 4]) ? 0x3F80u : 0u) | (((sk && qB[ro + 5]) ? 0x3F80u : 0u) << 16);
    unsigned int* dst = (unsigned int*)(xp + ro);
    dst[0] = wv0; dst[1] = wv1; dst[2] = wv2;
  }
}

// ---------------- K4: P GEMM (384x384 @ 384xcols) + bias + BN -> out fp32 -------------
__global__ __launch_bounds__(256) void k_proj(
    const u16* __restrict__ Pw, const u16* __restrict__ xp,
    const float4* __restrict__ PP, float* __restrict__ out) {
  const int jt = blockIdx.x, mt = blockIdx.y, b = blockIdx.z;
  const int tid = threadIdx.x;
  const int w = tid >> 6, l = tid & 63;
  const int wr = w >> 1, wc = w & 1;
  const int l15 = l & 15, g = l >> 4;
  const int m0 = mt * 128, j0 = jt * 128;

  __shared__ u16 Al[4096];
  __shared__ u16 Bl[4096];
  __shared__ float4 PRM[128];

  const u16* xb = xp + b * (COLS_B * 384);

  f32x4 acc[4][4];
  const f32x4 zero = {0.f, 0.f, 0.f, 0.f};
  #pragma unroll
  for (int mi = 0; mi < 4; ++mi)
    #pragma unroll
    for (int ni = 0; ni < 4; ++ni) acc[mi][ni] = zero;

  for (int ks = 0; ks < 12; ++ks) {
    const int k0 = ks * 32;
    #pragma unroll
    for (int q = 0; q < 2; ++q) {
      const int ch = w * 128 + q * 64 + l;
      const int row = ch >> 2, kc = (ch & 3) << 3;
      gll16(Pw + (m0 + row) * 384 + k0 + kc, &Al[(w * 128 + q * 64) * 8]);
      gll16(xb + (j0 + row) * 384 + k0 + kc, &Bl[(w * 128 + q * 64) * 8]);
    }
    __syncthreads();
    bf16x8 af[4], bfr[4];
    #pragma unroll
    for (int mi = 0; mi < 4; ++mi)
      af[mi] = *(const bf16x8*)&Al[(wr * 64 + mi * 16 + l15) * 32 + g * 8];
    #pragma unroll
    for (int ni = 0; ni < 4; ++ni)
      bfr[ni] = *(const bf16x8*)&Bl[(wc * 64 + ni * 16 + l15) * 32 + g * 8];
    #pragma unroll
    for (int mi = 0; mi < 4; ++mi)
      #pragma unroll
      for (int ni = 0; ni < 4; ++ni)
        acc[mi][ni] = __builtin_amdgcn_mfma_f32_16x16x32_bf16(af[mi], bfr[ni], acc[mi][ni], 0, 0, 0);
    __syncthreads();
  }

  if (tid < 128) PRM[tid] = PP[m0 + tid];
  __syncthreads();

  #pragma unroll
  for (int mi = 0; mi < 4; ++mi) {
    float4 pr0 = PRM[wr * 64 + mi * 16 + g * 4 + 0];
    float4 pr1 = PRM[wr * 64 + mi * 16 + g * 4 + 1];
    float4 pr2 = PRM[wr * 64 + mi * 16 + g * 4 + 2];
    float4 pr3 = PRM[wr * 64 + mi * 16 + g * 4 + 3];
    #pragma unroll
    for (int ni = 0; ni < 4; ++ni) {
      const int jc = j0 + wc * 64 + ni * 16 + l15;
      const int t = jc & 3, n = jc >> 2;
      float* ob = out + (((t * 16 + b) * 384) + m0 + wr * 64 + mi * 16 + g * 4) * 1024 + n;
      #pragma unroll
      for (int r = 0; r < 4; ++r) {
        float4 pr = (r == 0) ? pr0 : (r == 1) ? pr1 : (r == 2) ? pr2 : pr3;
        float zz = __fadd_rn(acc[mi][ni][r], pr.w);                        // + bias
        zz = __fadd_rn(__fmul_rn(__fsub_rn(zz, pr.y), pr.x), pr.z);        // BN, ref order
        ob[r * 1024] = zz;
      }
    }
  }
}

extern "C" void kernel_launch(void* const* d_in, const int* in_sizes, int n_in,
                              void* d_out, int out_size, void* d_ws, size_t ws_size,
                              hipStream_t stream) {
  (void)in_sizes; (void)n_in; (void)out_size; (void)ws_size;
  const float* x   = (const float*)d_in[0];
  const float* qw  = (const float*)d_in[1];
  const float* qg  = (const float*)d_in[2];
  const float* qbt = (const float*)d_in[3];
  const float* qm  = (const float*)d_in[4];
  const float* qv  = (const float*)d_in[5];
  const float* kw  = (const float*)d_in[6];
  const float* kg  = (const float*)d_in[7];
  const float* kbt = (const float*)d_in[8];
  const float* km  = (const float*)d_in[9];
  const float* kv  = (const float*)d_in[10];
  const float* vw  = (const float*)d_in[11];
  const float* vg  = (const float*)d_in[12];
  const float* vbt = (const float*)d_in[13];
  const float* vm  = (const float*)d_in[14];
  const float* vv  = (const float*)d_in[15];
  const float* pw  = (const float*)d_in[16];
  const float* pg  = (const float*)d_in[17];
  const float* pbt = (const float*)d_in[18];
  const float* pm  = (const float*)d_in[19];
  const float* pv  = (const float*)d_in[20];
  const float* pbias = (const float*)d_in[21];

  char* ws = (char*)d_ws;
  u16* xs    = (u16*)ws;                    // (B,N,T,C) bf16 spikes; later reused as xp
  u8*  sp    = (u8*)(ws + 50331648);        // q,k,v spike bytes, 3x ELEMS
  u16* Wstk  = (u16*)(ws + 125829120);      // [1152][384] bf16
  u16* Pw    = (u16*)(ws + 126713856);      // [384][384] bf16
  float4* BNP = (float4*)(ws + 127008768);  // [1152]
  float4* PP  = (float4*)(ws + 127027200);  // [384]

  k_convert<<<2310, 256, 0, stream>>>(qw, kw, vw, pw, qg, qbt, qm, qv, kg, kbt, km, kv,
                                      vg, vbt, vm, vv, pg, pbt, pm, pv, pbias,
                                      Wstk, Pw, BNP, PP);
  k_lif_in<<<dim3(16, 6, 16), 256, 0, stream>>>(x, xs);
  k_qkv<<<dim3(32, 9, 16), 256, 0, stream>>>(Wstk, xs, BNP, sp);
  k_attn<<<4096, 256, 0, stream>>>(sp, xs);          // xp aliases xs (xs dead after k_qkv)
  k_proj<<<dim3(32, 3, 16), 256, 0, stream>>>(Pw, xs, PP, (float*)d_out);
}

// Round 2
// 198.318 us; speedup vs baseline: 1.1366x; 1.1366x over previous
//
#include <hip/hip_runtime.h>

typedef unsigned short u16;
typedef unsigned char u8;
typedef unsigned int u32;
typedef float f32x4 __attribute__((ext_vector_type(4)));
typedef __bf16 bf16x8 __attribute__((ext_vector_type(8)));

#define ELEMS 25165824   // T*B*C*N bytes per spike branch = 4*16*384*1024
#define COLS_B 4096      // N*T per batch element
#define ONE_BF16 ((u16)0x3F80)

// ---- async global->LDS, 16B per lane, dest = wave-uniform base + lane*16 ----
__device__ __forceinline__ void gll16(const void* g, void* l) {
  __builtin_amdgcn_global_load_lds((const __attribute__((address_space(1))) void*)g,
                                   (__attribute__((address_space(3))) void*)l, 16, 0, 0);
}

// ---------------- K0: weights -> bf16 (stacked q,k,v), BN params fused ----------------
__global__ __launch_bounds__(256) void k_convert(
    const float* __restrict__ qw, const float* __restrict__ kw,
    const float* __restrict__ vw, const float* __restrict__ pw,
    const float* __restrict__ qg, const float* __restrict__ qbt,
    const float* __restrict__ qm, const float* __restrict__ qv,
    const float* __restrict__ kg, const float* __restrict__ kbt,
    const float* __restrict__ km, const float* __restrict__ kv,
    const float* __restrict__ vg, const float* __restrict__ vbt,
    const float* __restrict__ vm, const float* __restrict__ vv,
    const float* __restrict__ pg, const float* __restrict__ pbt,
    const float* __restrict__ pm, const float* __restrict__ pv,
    const float* __restrict__ pbias,
    u16* __restrict__ Wstk, u16* __restrict__ Pw,
    float4* __restrict__ BNP, float4* __restrict__ PP) {
  int tid = blockIdx.x * 256 + threadIdx.x;
  if (tid < 442368) {               // Wstk[1152][384]
    int r = tid / 384, c = tid - r * 384;
    const float* src = (r < 384) ? qw : (r < 768) ? kw : vw;
    int rr = (r >= 768) ? r - 768 : (r >= 384) ? r - 384 : r;
    unsigned int u = __float_as_uint(src[rr * 384 + c]);
    u = (u + 0x7FFFu + ((u >> 16) & 1u)) >> 16;   // RNE to bf16
    Wstk[tid] = (u16)u;
  } else if (tid < 589824) {        // Pw[384][384]
    int i = tid - 442368;
    unsigned int u = __float_as_uint(pw[i]);
    u = (u + 0x7FFFu + ((u >> 16) & 1u)) >> 16;
    Pw[i] = (u16)u;
  } else if (tid < 590976) {        // BNP[1152] = {inv, mean, beta, -}
    int r = tid - 589824;
    int br = r / 384, ch = r - br * 384;
    const float* g  = (br == 0) ? qg  : (br == 1) ? kg  : vg;
    const float* bt = (br == 0) ? qbt : (br == 1) ? kbt : vbt;
    const float* m  = (br == 0) ? qm  : (br == 1) ? km  : vm;
    const float* va = (br == 0) ? qv  : (br == 1) ? kv  : vv;
    float inv = g[ch] / sqrtf(va[ch] + 1e-5f);
    BNP[r] = make_float4(inv, m[ch], bt[ch], 0.f);
  } else if (tid < 591360) {        // PP[384] = {inv, mean, beta, bias}
    int ch = tid - 590976;
    float inv = pg[ch] / sqrtf(pv[ch] + 1e-5f);
    PP[ch] = make_float4(inv, pm[ch], pbt[ch], pbias[ch]);
  }
}

// ---------------- K1: input LIF + transpose (T,B,C,N)->(B,N,T,C) bf16 spikes ----------
__global__ __launch_bounds__(256) void k_lif_in(const float* __restrict__ x, u16* __restrict__ xs) {
  const int nt = blockIdx.x, ct = blockIdx.y, b = blockIdx.z;
  const int tid = threadIdx.x;
  const int nj = tid & 63, cr = tid >> 6;
  const int c0 = ct * 64, n0 = nt * 64;
  __shared__ u16 spl[16384];        // [nj][t][ci], ci XOR-swizzled by nj (quad-preserving)
  float v[16];
  #pragma unroll
  for (int i = 0; i < 16; ++i) v[i] = 0.f;
  for (int t = 0; t < 4; ++t) {
    const float* xr = x + (((t * 16 + b) * 384 + c0 + cr) * 1024) + n0 + nj;
    #pragma unroll
    for (int it = 0; it < 16; ++it) {
      float xv = xr[it * 4096];
      float vv = v[it];
      float h = __fadd_rn(vv, __fmul_rn(__fsub_rn(xv, vv), 0.5f));  // v + (x-v)/2, exact order
      bool s = h >= 1.f;
      v[it] = s ? 0.f : h;
      int ci = cr + it * 4;
      spl[((nj * 4 + t) << 6) | (ci ^ ((nj & 15) << 2))] = s ? ONE_BF16 : (u16)0;
    }
  }
  __syncthreads();
  #pragma unroll
  for (int kk = 0; kk < 16; ++kk) {
    int f = tid + kk * 256;
    int ci4 = f & 15, tt = (f >> 4) & 3, njj = f >> 6;
    ushort4 d = *(const ushort4*)&spl[((njj * 4 + tt) << 6) + ((ci4 * 4) ^ ((njj & 15) << 2))];
    *(ushort4*)&xs[((b * 1024 + n0 + njj) * 4 + tt) * 384 + c0 + ci4 * 4] = d;
  }
}

// ---------------- K2: stacked qkv GEMM (swapped operands) + BN + LIF -> sp u32 --------
// D[j, c] = sum_k xs[j][k] * W[c][k]; lane regs r=0..3 hold t=0..3 of one (n, c).
__global__ __launch_bounds__(256) void k_qkv(
    const u16* __restrict__ Wstk, const u16* __restrict__ xs,
    const float4* __restrict__ BNP, u8* __restrict__ sp) {
  const int jt = blockIdx.x, mt = blockIdx.y, b = blockIdx.z;
  const int tid = threadIdx.x;
  const int w = tid >> 6, l = tid & 63;
  const int wr = w >> 1, wc = w & 1;           // wr: j-half, wc: c-half
  const int l15 = l & 15, g = l >> 4;
  const int m0 = mt * 128, j0 = jt * 128;

  __shared__ u16 Al[4096];          // W tile   [128 c][32 k]
  __shared__ u16 Bl[4096];          // xs tile  [128 j][32 k]
  __shared__ float4 PRM[128];

  const u16* xb = xs + b * (COLS_B * 384);

  f32x4 acc[4][4];                  // [ji][ci]
  const f32x4 zero = {0.f, 0.f, 0.f, 0.f};
  #pragma unroll
  for (int ji = 0; ji < 4; ++ji)
    #pragma unroll
    for (int ci = 0; ci < 4; ++ci) acc[ji][ci] = zero;

  for (int ks = 0; ks < 12; ++ks) {
    const int k0 = ks * 32;
    #pragma unroll
    for (int q = 0; q < 2; ++q) {
      const int ch = w * 128 + q * 64 + l;
      const int row = ch >> 2, kc = (ch & 3) << 3;
      gll16(Wstk + (m0 + row) * 384 + k0 + kc, &Al[(w * 128 + q * 64) * 8]);
      gll16(xb + (j0 + row) * 384 + k0 + kc, &Bl[(w * 128 + q * 64) * 8]);
    }
    __syncthreads();
    bf16x8 ax[4], bw[4];
    #pragma unroll
    for (int ji = 0; ji < 4; ++ji)
      ax[ji] = *(const bf16x8*)&Bl[(wr * 64 + ji * 16 + l15) * 32 + g * 8];
    #pragma unroll
    for (int ci = 0; ci < 4; ++ci)
      bw[ci] = *(const bf16x8*)&Al[(wc * 64 + ci * 16 + l15) * 32 + g * 8];
    #pragma unroll
    for (int ji = 0; ji < 4; ++ji)
      #pragma unroll
      for (int ci = 0; ci < 4; ++ci)
        acc[ji][ci] = __builtin_amdgcn_mfma_f32_16x16x32_bf16(ax[ji], bw[ci], acc[ji][ci], 0, 0, 0);
    __syncthreads();
  }

  if (tid < 128) PRM[tid] = BNP[m0 + tid];
  __syncthreads();

  const int br = mt / 3;
  const int cb = (mt - br * 3) * 128;
  u32* spb = (u32*)(sp + (size_t)br * ELEMS) + ((size_t)(b * 1024 + jt * 32)) * 384 + cb;
  #pragma unroll
  for (int ci = 0; ci < 4; ++ci) {
    const int cloc = wc * 64 + ci * 16 + l15;
    float4 pr = PRM[cloc];
    #pragma unroll
    for (int ji = 0; ji < 4; ++ji) {
      f32x4 a = acc[ji][ci];
      u32 bytes = 0;
      float v = 0.f;
      #pragma unroll
      for (int t = 0; t < 4; ++t) {
        float z = __fadd_rn(__fmul_rn(__fsub_rn(a[t], pr.y), pr.x), pr.z);  // BN, ref order
        float h = __fadd_rn(v, __fmul_rn(__fsub_rn(z, v), 0.5f));            // LIF step
        bool s = h >= 1.f;
        v = s ? 0.f : h;
        bytes |= (s ? 1u : 0u) << (8 * t);
      }
      const int n_local = wr * 16 + ji * 4 + g;
      spb[n_local * 384 + cloc] = bytes;
    }
  }
}

// ---------------- K3: attn = sum_ch(k&v) per head (4 t in u32 bytes), LIF(0.5), xp ----
__global__ __launch_bounds__(256) void k_attn(const u8* __restrict__ sp, u16* __restrict__ xp) {
  const int gw = blockIdx.x * 4 + (threadIdx.x >> 6);
  const int l = threadIdx.x & 63;
  const int b = gw >> 10, n = gw & 1023;
  const u32* qB = (const u32*)sp;
  const u32* kB = (const u32*)(sp + ELEMS);
  const u32* vB = (const u32*)(sp + 2 * ELEMS);
  const int base = (b * 1024 + n) * 384 + l * 6;   // u32 index; lane covers 6 channels
  u32 qu[6], ku[6], vu[6];
  #pragma unroll
  for (int i = 0; i < 3; ++i) {
    *(uint2*)&qu[i * 2] = *(const uint2*)&qB[base + i * 2];
    *(uint2*)&ku[i * 2] = *(const uint2*)&kB[base + i * 2];
    *(uint2*)&vu[i * 2] = *(const uint2*)&vB[base + i * 2];
  }
  u32 s = 0;
  #pragma unroll
  for (int i = 0; i < 6; ++i) s += ku[i] & vu[i];   // 4 per-t byte sums in parallel
  s += __shfl_xor(s, 1);
  s += __shfl_xor(s, 2);
  s += __shfl_xor(s, 4);          // 8 lanes == one 48-channel head; bytes <= 48
  float v = 0.f;
  const int ob = ((b * 1024 + n) * 4) * 384 + l * 6;  // u16 index into xp
  #pragma unroll
  for (int t = 0; t < 4; ++t) {
    float attn = (float)((s >> (8 * t)) & 0xFFu);
    float h = __fadd_rn(v, __fmul_rn(__fsub_rn(attn, v), 0.5f));
    bool sk = h >= 0.5f;
    v = sk ? 0.f : h;
    u32 m = sk ? 0x3F80u : 0u;
    u32* dst = (u32*)(xp + ob + t * 384);
    #pragma unroll
    for (int i = 0; i < 3; ++i) {
      u32 lo = ((qu[2 * i]     >> (8 * t)) & 1u) ? m : 0u;
      u32 hi = ((qu[2 * i + 1] >> (8 * t)) & 1u) ? m : 0u;
      dst[i] = lo | (hi << 16);
    }
  }
}

// ---------------- K4: P GEMM (384x384 @ 384xcols) + bias + BN -> out fp32 -------------
__global__ __launch_bounds__(256) void k_proj(
    const u16* __restrict__ Pw, const u16* __restrict__ xp,
    const float4* __restrict__ PP, float* __restrict__ out) {
  const int jt = blockIdx.x, mt = blockIdx.y, b = blockIdx.z;
  const int tid = threadIdx.x;
  const int w = tid >> 6, l = tid & 63;
  const int wr = w >> 1, wc = w & 1;
  const int l15 = l & 15, g = l >> 4;
  const int m0 = mt * 128, j0 = jt * 128;

  __shared__ u16 Al[4096];
  __shared__ u16 Bl[4096];
  __shared__ float4 PRM[128];

  const u16* xb = xp + b * (COLS_B * 384);

  f32x4 acc[4][4];
  const f32x4 zero = {0.f, 0.f, 0.f, 0.f};
  #pragma unroll
  for (int mi = 0; mi < 4; ++mi)
    #pragma unroll
    for (int ni = 0; ni < 4; ++ni) acc[mi][ni] = zero;

  for (int ks = 0; ks < 12; ++ks) {
    const int k0 = ks * 32;
    #pragma unroll
    for (int q = 0; q < 2; ++q) {
      const int ch = w * 128 + q * 64 + l;
      const int row = ch >> 2, kc = (ch & 3) << 3;
      gll16(Pw + (m0 + row) * 384 + k0 + kc, &Al[(w * 128 + q * 64) * 8]);
      gll16(xb + (j0 + row) * 384 + k0 + kc, &Bl[(w * 128 + q * 64) * 8]);
    }
    __syncthreads();
    bf16x8 af[4], bfr[4];
    #pragma unroll
    for (int mi = 0; mi < 4; ++mi)
      af[mi] = *(const bf16x8*)&Al[(wr * 64 + mi * 16 + l15) * 32 + g * 8];
    #pragma unroll
    for (int ni = 0; ni < 4; ++ni)
      bfr[ni] = *(const bf16x8*)&Bl[(wc * 64 + ni * 16 + l15) * 32 + g * 8];
    #pragma unroll
    for (int mi = 0; mi < 4; ++mi)
      #pragma unroll
      for (int ni = 0; ni < 4; ++ni)
        acc[mi][ni] = __builtin_amdgcn_mfma_f32_16x16x32_bf16(af[mi], bfr[ni], acc[mi][ni], 0, 0, 0);
    __syncthreads();
  }

  if (tid < 128) PRM[tid] = PP[m0 + tid];
  __syncthreads();

  #pragma unroll
  for (int mi = 0; mi < 4; ++mi) {
    float4 pr0 = PRM[wr * 64 + mi * 16 + g * 4 + 0];
    float4 pr1 = PRM[wr * 64 + mi * 16 + g * 4 + 1];
    float4 pr2 = PRM[wr * 64 + mi * 16 + g * 4 + 2];
    float4 pr3 = PRM[wr * 64 + mi * 16 + g * 4 + 3];
    #pragma unroll
    for (int ni = 0; ni < 4; ++ni) {
      const int jc = j0 + wc * 64 + ni * 16 + l15;
      const int t = jc & 3, n = jc >> 2;
      float* ob = out + (((t * 16 + b) * 384) + m0 + wr * 64 + mi * 16 + g * 4) * 1024 + n;
      #pragma unroll
      for (int r = 0; r < 4; ++r) {
        float4 pr = (r == 0) ? pr0 : (r == 1) ? pr1 : (r == 2) ? pr2 : pr3;
        float zz = __fadd_rn(acc[mi][ni][r], pr.w);                        // + bias
        zz = __fadd_rn(__fmul_rn(__fsub_rn(zz, pr.y), pr.x), pr.z);        // BN, ref order
        ob[r * 1024] = zz;
      }
    }
  }
}

extern "C" void kernel_launch(void* const* d_in, const int* in_sizes, int n_in,
                              void* d_out, int out_size, void* d_ws, size_t ws_size,
                              hipStream_t stream) {
  (void)in_sizes; (void)n_in; (void)out_size; (void)ws_size;
  const float* x   = (const float*)d_in[0];
  const float* qw  = (const float*)d_in[1];
  const float* qg  = (const float*)d_in[2];
  const float* qbt = (const float*)d_in[3];
  const float* qm  = (const float*)d_in[4];
  const float* qv  = (const float*)d_in[5];
  const float* kw  = (const float*)d_in[6];
  const float* kg  = (const float*)d_in[7];
  const float* kbt = (const float*)d_in[8];
  const float* km  = (const float*)d_in[9];
  const float* kv  = (const float*)d_in[10];
  const float* vw  = (const float*)d_in[11];
  const float* vg  = (const float*)d_in[12];
  const float* vbt = (const float*)d_in[13];
  const float* vm  = (const float*)d_in[14];
  const float* vv  = (const float*)d_in[15];
  const float* pw  = (const float*)d_in[16];
  const float* pg  = (const float*)d_in[17];
  const float* pbt = (const float*)d_in[18];
  const float* pm  = (const float*)d_in[19];
  const float* pv  = (const float*)d_in[20];
  const float* pbias = (const float*)d_in[21];

  char* ws = (char*)d_ws;
  u16* xs    = (u16*)ws;                    // (B,N,T,C) bf16 spikes; later reused as xp
  u8*  sp    = (u8*)(ws + 50331648);        // q,k,v spikes, u32 per (n,c): [b][n][c][t]
  u16* Wstk  = (u16*)(ws + 125829120);      // [1152][384] bf16
  u16* Pw    = (u16*)(ws + 126713856);      // [384][384] bf16
  float4* BNP = (float4*)(ws + 127008768);  // [1152]
  float4* PP  = (float4*)(ws + 127027200);  // [384]

  k_convert<<<2310, 256, 0, stream>>>(qw, kw, vw, pw, qg, qbt, qm, qv, kg, kbt, km, kv,
                                      vg, vbt, vm, vv, pg, pbt, pm, pv, pbias,
                                      Wstk, Pw, BNP, PP);
  k_lif_in<<<dim3(16, 6, 16), 256, 0, stream>>>(x, xs);
  k_qkv<<<dim3(32, 9, 16), 256, 0, stream>>>(Wstk, xs, BNP, sp);
  k_attn<<<4096, 256, 0, stream>>>(sp, xs);          // xp aliases xs (xs dead after k_qkv)
  k_proj<<<dim3(32, 3, 16), 256, 0, stream>>>(Pw, xs, PP, (float*)d_out);
}